// Round 1
// baseline (220.497 us; speedup 1.0000x reference)
//
#include <hip/hip_runtime.h>
#include <float.h>

// Problem constants (B=16, N=M=4096, fp32, 3-D points)
#define BATCH   16
#define NPTS    4096
#define TOTALP  (BATCH * NPTS)      // 65536 points per set

// ---------------------------------------------------------------------------
// Pack kernel: xyz (3 floats) -> xyzw (float4) with w = 0.5*||p||^2.
// Also zeroes d_out (it is poisoned 0xAA before every timed launch).
// ---------------------------------------------------------------------------
__global__ __launch_bounds__(256) void pack_kernel(
    const float* __restrict__ xyz1, const float* __restrict__ xyz2,
    float4* __restrict__ p1, float4* __restrict__ p2,
    float* __restrict__ out)
{
    int i = blockIdx.x * 256 + threadIdx.x;
    if (i == 0) { out[0] = 0.0f; out[1] = 0.0f; }
    const float* src = (i < TOTALP) ? xyz1 : xyz2;
    float4*      dst = (i < TOTALP) ? p1   : p2;
    int j = (i < TOTALP) ? i : (i - TOTALP);
    float x = src[3 * j + 0];
    float y = src[3 * j + 1];
    float z = src[3 * j + 2];
    dst[j] = make_float4(x, y, z, 0.5f * (x * x + y * y + z * z));
}

// ---------------------------------------------------------------------------
// Fused chamfer kernel, both directions in one grid.
// blocks 0..255   : dir 0 (set1 -> set2), output out[0]
// blocks 256..511 : dir 1 (set2 -> set1), output out[1]
// Each thread owns one query point (in VGPRs); the opposite set is streamed
// with wave-uniform loads (compiler promotes to s_load_dwordx16).
// Inner loop: 3 FMA + 1 min per pair.
//   t_m = w_m - x . p_m   where w_m = 0.5*||p_m||^2
//   d_min = 2*w_own + 2*min_m t_m  ==  min_m ||x - p_m||^2
// ---------------------------------------------------------------------------
__global__ __launch_bounds__(256) void chamfer_kernel(
    const float4* __restrict__ pack1, const float4* __restrict__ pack2,
    float* __restrict__ out)
{
    const int blk = blockIdx.x;
    const int dir = blk >> 8;          // 0 or 1
    const int idx = blk & 255;
    const int b   = idx >> 4;          // 16 blocks per batch (4096/256)
    const int n0  = (idx & 15) << 8;   // 256 query points per block

    const float4* __restrict__ own = (dir == 0 ? pack1 : pack2) + b * NPTS;
    const float4* __restrict__ opp = (dir == 0 ? pack2 : pack1) + b * NPTS;

    const int n = n0 + threadIdx.x;
    const float4 a = own[n];
    const float nx = -a.x, ny = -a.y, nz = -a.z;

    float m0 = FLT_MAX, m1 = FLT_MAX;

    for (int m = 0; m < NPTS; m += 8) {
        float t[8];
#pragma unroll
        for (int u = 0; u < 8; ++u) {
            const float4 p = opp[m + u];            // wave-uniform -> s_load
            float s = fmaf(nz, p.z, p.w);
            s = fmaf(ny, p.y, s);
            s = fmaf(nx, p.x, s);
            t[u] = s;
        }
        m0 = fminf(m0, fminf(fminf(t[0], t[1]), fminf(t[2], t[3])));
        m1 = fminf(m1, fminf(fminf(t[4], t[5]), fminf(t[6], t[7])));
    }

    // d = ||x||^2 + 2 * min_m t_m ;  a.w = 0.5*||x||^2
    float d = 2.0f * a.w + 2.0f * fminf(m0, m1);

    // --- block reduction of sum(d), then one atomic per block ---
    for (int off = 32; off > 0; off >>= 1)
        d += __shfl_down(d, off);

    __shared__ float wsum[4];
    const int lane = threadIdx.x & 63;
    const int wv   = threadIdx.x >> 6;
    if (lane == 0) wsum[wv] = d;
    __syncthreads();
    if (threadIdx.x == 0) {
        float s = wsum[0] + wsum[1] + wsum[2] + wsum[3];
        atomicAdd(&out[dir], s * (1.0f / (float)TOTALP));
    }
}

// ---------------------------------------------------------------------------
// Fallback path (only if workspace is too small for packing): direct 7-op
// distance from raw xyz, still wave-uniform scalar streaming.
// ---------------------------------------------------------------------------
__global__ void zero_out_kernel(float* __restrict__ out)
{
    if (threadIdx.x == 0) { out[0] = 0.0f; out[1] = 0.0f; }
}

__global__ __launch_bounds__(256) void chamfer_raw_kernel(
    const float* __restrict__ xyz1, const float* __restrict__ xyz2,
    float* __restrict__ out)
{
    const int blk = blockIdx.x;
    const int dir = blk >> 8;
    const int idx = blk & 255;
    const int b   = idx >> 4;
    const int n0  = (idx & 15) << 8;

    const float* __restrict__ own = (dir == 0 ? xyz1 : xyz2) + b * NPTS * 3;
    const float* __restrict__ opp = (dir == 0 ? xyz2 : xyz1) + b * NPTS * 3;

    const int n = n0 + threadIdx.x;
    const float ax = own[3 * n + 0];
    const float ay = own[3 * n + 1];
    const float az = own[3 * n + 2];

    float best = FLT_MAX;
    for (int m = 0; m < NPTS; m += 4) {
#pragma unroll
        for (int u = 0; u < 4; ++u) {
            const float px = opp[3 * (m + u) + 0];
            const float py = opp[3 * (m + u) + 1];
            const float pz = opp[3 * (m + u) + 2];
            const float dx = px - ax, dy = py - ay, dz = pz - az;
            float d = dx * dx;
            d = fmaf(dy, dy, d);
            d = fmaf(dz, dz, d);
            best = fminf(best, d);
        }
    }

    float d = best;
    for (int off = 32; off > 0; off >>= 1)
        d += __shfl_down(d, off);

    __shared__ float wsum[4];
    const int lane = threadIdx.x & 63;
    const int wv   = threadIdx.x >> 6;
    if (lane == 0) wsum[wv] = d;
    __syncthreads();
    if (threadIdx.x == 0) {
        float s = wsum[0] + wsum[1] + wsum[2] + wsum[3];
        atomicAdd(&out[dir], s * (1.0f / (float)TOTALP));
    }
}

// ---------------------------------------------------------------------------
extern "C" void kernel_launch(void* const* d_in, const int* in_sizes, int n_in,
                              void* d_out, int out_size, void* d_ws, size_t ws_size,
                              hipStream_t stream)
{
    const float* xyz1 = (const float*)d_in[0];
    const float* xyz2 = (const float*)d_in[1];
    float* out = (float*)d_out;

    const size_t packed_bytes = (size_t)TOTALP * sizeof(float4);   // 1 MiB per set

    if (ws_size >= 2 * packed_bytes) {
        float4* p1 = (float4*)d_ws;
        float4* p2 = (float4*)((char*)d_ws + packed_bytes);

        pack_kernel<<<(2 * TOTALP) / 256, 256, 0, stream>>>(xyz1, xyz2, p1, p2, out);
        chamfer_kernel<<<512, 256, 0, stream>>>(p1, p2, out);
    } else {
        zero_out_kernel<<<1, 64, 0, stream>>>(out);
        chamfer_raw_kernel<<<512, 256, 0, stream>>>(xyz1, xyz2, out);
    }
}